// Round 1
// baseline (818.204 us; speedup 1.0000x reference)
//
#include <hip/hip_runtime.h>

#define NCLS 80
#define CONF_T 0.25f
#define P1_BLOCKS 2048
#define P1_THREADS 256

// ws layout: [0] int first_fail ; [256 bytes ...] float partials[P1_BLOCKS]

__global__ void init_fail(int* fail, int N) { *fail = N; }

__device__ __forceinline__ float row_val_global(const float* __restrict__ pr,
                                                const float* __restrict__ boxes,
                                                int row, float* score_out) {
    const float4* p = (const float4*)(pr + (size_t)row * NCLS);
    float m = -INFINITY;
#pragma unroll
    for (int k = 0; k < NCLS / 4; ++k) {
        float4 v = p[k];
        m = fmaxf(m, fmaxf(fmaxf(v.x, v.y), fmaxf(v.z, v.w)));
    }
    float4 b = ((const float4*)boxes)[row];
    *score_out = m;
    return m + b.x + b.y + b.z + b.w;
}

__device__ __forceinline__ float block_reduce_sum(float v) {
#pragma unroll
    for (int off = 32; off > 0; off >>= 1) v += __shfl_down(v, off, 64);
    __shared__ float sred[P1_THREADS / 64];
    int lane = threadIdx.x & 63;
    int wid  = threadIdx.x >> 6;
    if (lane == 0) sred[wid] = v;
    __syncthreads();
    float total = 0.f;
    if (threadIdx.x == 0) {
#pragma unroll
        for (int w = 0; w < P1_THREADS / 64; ++w) total += sred[w];
    }
    return total; // valid on thread 0 only
}

// Register-direct streaming pass: 4 lanes per row, no LDS staging, no barriers.
// Block b owns contiguous rows [b*R, min((b+1)*R, N)) so pass2's prefix logic holds.
__global__ __launch_bounds__(P1_THREADS) void pass1(const float* __restrict__ pr,
                                                    const float* __restrict__ boxes,
                                                    float* __restrict__ partials,
                                                    int* __restrict__ fail,
                                                    int N, int R) {
    const int t    = (int)threadIdx.x;
    const int lane = t & 63;
    const int w    = t >> 6;   // wave id 0..3
    const int sub  = lane & 3; // which float4-column slot of the row (0..3)
    const int g    = lane >> 2;// which of the 16 rows this wave covers per step

    const int row0   = (int)blockIdx.x * R;
    const int rowEnd = min(row0 + R, N);

    float acc = 0.f;

    // Wave w covers rows [base, base+16) each step; 4 waves stride 64 rows.
    for (int base = row0 + (w << 4); base < rowEnd; base += 64) {
        const int row = base + g; // uniform across the 4-lane group
        if (row < rowEnd) {
            // Each instruction: 16 groups x 64B contiguous chunks (stride 320B),
            // fully-utilized cache lines, same 16-line txn count as a dense wave load.
            const float4* p = (const float4*)(pr + (size_t)row * NCLS) + sub;
            float4 v0 = p[0];
            float4 v1 = p[4];
            float4 v2 = p[8];
            float4 v3 = p[12];
            float4 v4 = p[16];
            float m0 = fmaxf(fmaxf(v0.x, v0.y), fmaxf(v0.z, v0.w));
            float m1 = fmaxf(fmaxf(v1.x, v1.y), fmaxf(v1.z, v1.w));
            float m2 = fmaxf(fmaxf(v2.x, v2.y), fmaxf(v2.z, v2.w));
            float m3 = fmaxf(fmaxf(v3.x, v3.y), fmaxf(v3.z, v3.w));
            float m4 = fmaxf(fmaxf(v4.x, v4.y), fmaxf(v4.z, v4.w));
            float m  = fmaxf(fmaxf(fmaxf(m0, m1), fmaxf(m2, m3)), m4);
            // row max across the 4-lane group (exact: max is order-independent)
            m = fmaxf(m, __shfl_xor(m, 1, 64));
            m = fmaxf(m, __shfl_xor(m, 2, 64));

            // box components: one float per lane, 64x4B fully coalesced.
            // Any within-block distribution is fine: pass2 discards/recomputes
            // the straddling block, so only whole-block sums matter.
            acc += boxes[(size_t)row * 4 + sub];

            if (sub == 0) {
                if (m < CONF_T) atomicMin(fail, row);
                acc += m;
            }
        }
    }

    float tot = block_reduce_sum(acc);
    if (t == 0) partials[blockIdx.x] = tot;
}

__global__ __launch_bounds__(P1_THREADS) void pass2(const float* __restrict__ pr,
                                                    const float* __restrict__ boxes,
                                                    const float* __restrict__ partials,
                                                    const int* __restrict__ fail,
                                                    float* __restrict__ out,
                                                    int N, int R) {
    int ff = *fail;
    if (ff > N) ff = N;
    if (ff < 0) ff = 0;

    int full, start;
    if (ff >= N) { full = P1_BLOCKS; start = N; }       // common case: keep everything
    else         { full = ff / R;    start = full * R; } // straddling chunk recomputed

    float acc = 0.f;
    for (int c = (int)threadIdx.x; c < full; c += P1_THREADS) acc += partials[c];
    for (int row = start + (int)threadIdx.x; row < ff; row += P1_THREADS) {
        float score;
        acc += row_val_global(pr, boxes, row, &score);
    }
    float tot = block_reduce_sum(acc);
    if (threadIdx.x == 0) *out = tot;
}

extern "C" void kernel_launch(void* const* d_in, const int* in_sizes, int n_in,
                              void* d_out, int out_size, void* d_ws, size_t ws_size,
                              hipStream_t stream) {
    const float* pr    = (const float*)d_in[0];
    const float* boxes = (const float*)d_in[1];
    float* out = (float*)d_out;

    int N = in_sizes[1] / 4; // boxes are (N,4)

    // rows per block: ceil(N/blocks) rounded up to the 64-row block step
    int rpb = (N + P1_BLOCKS - 1) / P1_BLOCKS;
    int R   = (rpb + 63) & ~63;

    int*   fail     = (int*)d_ws;
    float* partials = (float*)((char*)d_ws + 256);

    init_fail<<<1, 1, 0, stream>>>(fail, N);
    pass1<<<P1_BLOCKS, P1_THREADS, 0, stream>>>(pr, boxes, partials, fail, N, R);
    pass2<<<1, P1_THREADS, 0, stream>>>(pr, boxes, partials, fail, out, N, R);
}

// Round 3
// 813.062 us; speedup vs baseline: 1.0063x; 1.0063x over previous
//
#include <hip/hip_runtime.h>

#define NCLS 80
#define CONF_T 0.25f
#define P1_BLOCKS 2048
#define P1_THREADS 256

// ws layout: [0] int first_fail ; [256 bytes ...] float partials[P1_BLOCKS]

__global__ void init_fail(int* fail, int N) { *fail = N; }

__device__ __forceinline__ float row_val_global(const float* __restrict__ pr,
                                                const float* __restrict__ boxes,
                                                int row, float* score_out) {
    const float4* p = (const float4*)(pr + (size_t)row * NCLS);
    float m = -INFINITY;
#pragma unroll
    for (int k = 0; k < NCLS / 4; ++k) {
        float4 v = p[k];
        m = fmaxf(m, fmaxf(fmaxf(v.x, v.y), fmaxf(v.z, v.w)));
    }
    float4 b = ((const float4*)boxes)[row];
    *score_out = m;
    return m + b.x + b.y + b.z + b.w;
}

__device__ __forceinline__ float block_reduce_sum(float v) {
#pragma unroll
    for (int off = 32; off > 0; off >>= 1) v += __shfl_down(v, off, 64);
    __shared__ float sred[P1_THREADS / 64];
    int lane = threadIdx.x & 63;
    int wid  = threadIdx.x >> 6;
    if (lane == 0) sred[wid] = v;
    __syncthreads();
    float total = 0.f;
    if (threadIdx.x == 0) {
#pragma unroll
        for (int w = 0; w < P1_THREADS / 64; ++w) total += sred[w];
    }
    return total; // valid on thread 0 only
}

__device__ __forceinline__ float f4max(float4 v) {
    return fmaxf(fmaxf(v.x, v.y), fmaxf(v.z, v.w));
}

// Register-direct streaming pass, 4 lanes per row.
// Hot loop is guard-free and atomic-free: fail rows tracked in a register,
// one atomicMin per thread after the loop. x2 unroll -> 12 loads in flight.
// Block b owns contiguous rows [b*R, min((b+1)*R, N)) so pass2's prefix logic holds.
__global__ __launch_bounds__(P1_THREADS) void pass1(const float* __restrict__ pr,
                                                    const float* __restrict__ boxes,
                                                    float* __restrict__ partials,
                                                    int* __restrict__ fail,
                                                    int N, int R) {
    const int t    = (int)threadIdx.x;
    const int lane = t & 63;
    const int w    = t >> 6;   // wave id 0..3
    const int sub  = lane & 3; // float4-column slot within the row (0..3)
    const int g    = lane >> 2;// row index within the wave's 16-row group

    const int row0 = (int)blockIdx.x * R;
    float acc  = 0.f;
    int   fmin = N; // first failing row seen by this thread

    if (row0 + R <= N) {
        // ---------- full block: guard-free, unrolled x2 ----------
        const int   myrow0 = row0 + (w << 4) + g;          // this lane's first row
        const float* bx    = boxes + (size_t)row0 * 4;     // block's box base

        for (int base = 0; base < R; base += 128) {        // R is a multiple of 128
            const int rowA = myrow0 + base;
            const int rowB = rowA + 64;
            const float4* pA = (const float4*)(pr + (size_t)rowA * NCLS) + sub;
            const float4* pB = (const float4*)(pr + (size_t)rowB * NCLS) + sub;
            // 10 dwordx4 + 2 dword issued before any use
            float4 a0 = pA[0], a1 = pA[4], a2 = pA[8], a3 = pA[12], a4 = pA[16];
            float4 b0 = pB[0], b1 = pB[4], b2 = pB[8], b3 = pB[12], b4 = pB[16];
            float bA = bx[(size_t)(base << 2) + (w << 6) + lane];          // boxes for rowA group
            float bB = bx[(size_t)(base << 2) + 256 + (w << 6) + lane];   // boxes for rowB group

            float mA = fmaxf(fmaxf(fmaxf(f4max(a0), f4max(a1)),
                                   fmaxf(f4max(a2), f4max(a3))), f4max(a4));
            float mB = fmaxf(fmaxf(fmaxf(f4max(b0), f4max(b1)),
                                   fmaxf(f4max(b2), f4max(b3))), f4max(b4));
            // row max across the 4-lane group (exact: max is order-independent)
            mA = fmaxf(mA, __shfl_xor(mA, 1, 64));
            mA = fmaxf(mA, __shfl_xor(mA, 2, 64));
            mB = fmaxf(mB, __shfl_xor(mB, 1, 64));
            mB = fmaxf(mB, __shfl_xor(mB, 2, 64));

            acc += bA + bB; // box components; whole-block sum is all that matters
            if (sub == 0) {
                if (mA < CONF_T) fmin = min(fmin, rowA);
                if (mB < CONF_T) fmin = min(fmin, rowB);
                acc += mA + mB;
            }
        }
    } else if (row0 < N) {
        // ---------- single partial block: simple per-thread rows ----------
        for (int row = row0 + t; row < N; row += P1_THREADS) {
            float score;
            acc += row_val_global(pr, boxes, row, &score);
            if (score < CONF_T) fmin = min(fmin, row);
        }
    }

    if (fmin < N) atomicMin(fail, fmin); // essentially never taken on this data

    float tot = block_reduce_sum(acc);
    if (t == 0) partials[blockIdx.x] = tot;
}

__global__ __launch_bounds__(P1_THREADS) void pass2(const float* __restrict__ pr,
                                                    const float* __restrict__ boxes,
                                                    const float* __restrict__ partials,
                                                    const int* __restrict__ fail,
                                                    float* __restrict__ out,
                                                    int N, int R) {
    int ff = *fail;
    if (ff > N) ff = N;
    if (ff < 0) ff = 0;

    int full, start;
    if (ff >= N) { full = P1_BLOCKS; start = N; }       // common case: keep everything
    else         { full = min(ff / R, P1_BLOCKS); start = full * R; } // straddling chunk recomputed

    float acc = 0.f;
    for (int c = (int)threadIdx.x; c < full; c += P1_THREADS) acc += partials[c];
    for (int row = start + (int)threadIdx.x; row < ff; row += P1_THREADS) {
        float score;
        acc += row_val_global(pr, boxes, row, &score);
    }
    float tot = block_reduce_sum(acc);
    if (threadIdx.x == 0) *out = tot;
}

extern "C" void kernel_launch(void* const* d_in, const int* in_sizes, int n_in,
                              void* d_out, int out_size, void* d_ws, size_t ws_size,
                              hipStream_t stream) {
    const float* pr    = (const float*)d_in[0];
    const float* boxes = (const float*)d_in[1];
    float* out = (float*)d_out;

    int N = in_sizes[1] / 4; // boxes are (N,4)

    // rows per block, rounded up to the 128-row unroll step
    int rpb = (N + P1_BLOCKS - 1) / P1_BLOCKS;
    int R   = (rpb + 127) & ~127;

    int*   fail     = (int*)d_ws;
    float* partials = (float*)((char*)d_ws + 256);

    init_fail<<<1, 1, 0, stream>>>(fail, N);
    pass1<<<P1_BLOCKS, P1_THREADS, 0, stream>>>(pr, boxes, partials, fail, N, R);
    pass2<<<1, P1_THREADS, 0, stream>>>(pr, boxes, partials, fail, out, N, R);
}